// Round 1
// baseline (345.545 us; speedup 1.0000x reference)
//
#include <hip/hip_runtime.h>
#include <math.h>

namespace {
constexpr int kB  = 16;
constexpr int kC  = 256;
constexpr int kM  = 1024;
constexpr int kOC = 144;   // 64 Q + 16 K + 64 V channels

// ---------------------------------------------------------------------------
// K1: fused conv1x1 (Q,K,V) + BN.  qkv[b][oc][m], oc: 0..63 Q(h*16+k), 64..79 K, 80..143 V
// grid (16 m-tiles, 16 b), block 256
// ---------------------------------------------------------------------------
__global__ __launch_bounds__(256) void k_qkv(
    const float* __restrict__ x,  const float* __restrict__ Wq,
    const float* __restrict__ Wk, const float* __restrict__ Wv,
    const float* __restrict__ gq, const float* __restrict__ bq,
    const float* __restrict__ mq, const float* __restrict__ vq,
    const float* __restrict__ gv, const float* __restrict__ bv,
    const float* __restrict__ mv, const float* __restrict__ vv,
    float* __restrict__ qkv)
{
    __shared__ float xs[64][68];    // [ci][mi], padded for bank spread + f4 align
    __shared__ float Ws[64][145];   // [ci][oc], padded (17*ci + oc) -> 2-way max

    const int b  = blockIdx.y;
    const int m0 = blockIdx.x * 64;
    const int t  = threadIdx.x;
    const int mi4 = (t & 15) * 4;   // 4 consecutive m per thread
    const int ocg = t >> 4;         // 16 groups x 9 output channels

    float acc[9][4];
#pragma unroll
    for (int j = 0; j < 9; ++j)
#pragma unroll
        for (int i = 0; i < 4; ++i) acc[j][i] = 0.f;

    const int ciL = t & 63;
    const int ocq = t >> 6;

    for (int cc = 0; cc < 4; ++cc) {
        const int c0 = cc * 64;
#pragma unroll
        for (int j = 0; j < 16; ++j) {
            int e = t + 256 * j;
            int ci = e >> 6, mm = e & 63;
            xs[ci][mm] = x[(size_t)(b * kC + c0 + ci) * kM + m0 + mm];
        }
#pragma unroll
        for (int j = 0; j < 36; ++j) {
            int oc = ocq + 4 * j;
            const float* wrow = (oc < 64) ? (Wq + oc * kC)
                               : (oc < 80) ? (Wk + (oc - 64) * kC)
                                           : (Wv + (oc - 80) * kC);
            Ws[ciL][oc] = wrow[c0 + ciL];
        }
        __syncthreads();
#pragma unroll 8
        for (int ci = 0; ci < 64; ++ci) {
            const float4 xv = *(const float4*)&xs[ci][mi4];
#pragma unroll
            for (int j = 0; j < 9; ++j) {
                const float w = Ws[ci][ocg * 9 + j];
                acc[j][0] += w * xv.x;
                acc[j][1] += w * xv.y;
                acc[j][2] += w * xv.z;
                acc[j][3] += w * xv.w;
            }
        }
        __syncthreads();
    }

    // BN + store (coalesced float4 rows over m)
#pragma unroll
    for (int j = 0; j < 9; ++j) {
        const int oc = ocg * 9 + j;
        float s, bb;
        if (oc < 64)      { float inv = rsqrtf(vq[oc] + 1e-5f);      s = inv * gq[oc];      bb = bq[oc]      - mq[oc]      * s; }
        else if (oc < 80) { s = 1.f; bb = 0.f; }
        else              { int i2 = oc - 80; float inv = rsqrtf(vv[i2] + 1e-5f); s = inv * gv[i2]; bb = bv[i2] - mv[i2] * s; }
        float4 o;
        o.x = acc[j][0] * s + bb;
        o.y = acc[j][1] * s + bb;
        o.z = acc[j][2] * s + bb;
        o.w = acc[j][3] * s + bb;
        *(float4*)&qkv[(size_t)(b * kOC + oc) * kM + m0 + mi4] = o;
    }
}

// ---------------------------------------------------------------------------
// K2: sK = softmax_k(K); partial lam_c[b][k][v] = sum_{m in block} sK[m,k] V[m,v]
// grid (8 m-blocks, 16 b), block 256.  lam_parts[mb][b][k][v]
// ---------------------------------------------------------------------------
__global__ __launch_bounds__(256) void k_lam(
    const float* __restrict__ qkv, float* __restrict__ lam_parts)
{
    __shared__ float Ks[16][128];
    __shared__ float Vsh[64][129];

    const int b = blockIdx.y, mb = blockIdx.x;
    const int m0 = mb * 128;
    const int t = threadIdx.x;
    const float* Kc = qkv + (size_t)(b * kOC + 64) * kM + m0;
    const float* Vc = qkv + (size_t)(b * kOC + 80) * kM + m0;

#pragma unroll
    for (int j = 0; j < 8; ++j) {
        int e = t + 256 * j;
        Ks[e >> 7][e & 127] = Kc[(size_t)(e >> 7) * kM + (e & 127)];
    }
#pragma unroll
    for (int j = 0; j < 32; ++j) {
        int e = t + 256 * j;
        Vsh[e >> 7][e & 127] = Vc[(size_t)(e >> 7) * kM + (e & 127)];
    }
    __syncthreads();

    if (t < 128) {
        float vals[16];
        float mx = -1e30f;
#pragma unroll
        for (int k = 0; k < 16; ++k) { vals[k] = Ks[k][t]; mx = fmaxf(mx, vals[k]); }
        float sum = 0.f;
#pragma unroll
        for (int k = 0; k < 16; ++k) { vals[k] = __expf(vals[k] - mx); sum += vals[k]; }
        const float inv = 1.f / sum;
#pragma unroll
        for (int k = 0; k < 16; ++k) Ks[k][t] = vals[k] * inv;
    }
    __syncthreads();

    const int v = t & 63, kq = t >> 6;
    float a[4] = {0.f, 0.f, 0.f, 0.f};
    for (int mm = 0; mm < 128; ++mm) {
        const float vv_ = Vsh[v][mm];
#pragma unroll
        for (int j = 0; j < 4; ++j) a[j] += Ks[kq * 4 + j][mm] * vv_;
    }
    float* o = lam_parts + (size_t)(mb * kB + b) * 1024;
#pragma unroll
    for (int j = 0; j < 4; ++j) o[(kq * 4 + j) * 64 + v] = a[j];
}

// ---------------------------------------------------------------------------
// K3: out[b,n,h,v] = sum_k Q[h,n,k] lam_c[k,v]  +  sum_m S[h,n,m] V[m,v]
//     S[h,n,m] = sum_k Q[h,n,k] * rpe[m/32-n/32+31][m%32-n%32+31][k]
// grid (32 n-rows, 16 b), block 256
// ---------------------------------------------------------------------------
__global__ __launch_bounds__(256) void k_attn(
    const float* __restrict__ qkv, const float* __restrict__ lam_parts,
    const float* __restrict__ rpe, float* __restrict__ out)
{
    __shared__ float  lam_s[16][64];   // 4 KB
    __shared__ float  Rs[63][20];      // rpe row slice, stride 20 -> even bank spread
    __shared__ float  Vs[32][68];      // [ml][v], stride 68 (17 f4)
    __shared__ float4 S4[32][33];      // [ml][nl] -> (s_h0..s_h3)

    const int b = blockIdx.y, nrow = blockIdx.x;
    const int n0 = nrow * 32;
    const int t = threadIdx.x;

    // lam_c = sum of 8 partials
    for (int e = t; e < 1024; e += 256) {
        float s = 0.f;
        for (int p = 0; p < 8; ++p) s += lam_parts[(size_t)(p * kB + b) * 1024 + e];
        lam_s[e >> 6][e & 63] = s;
    }
    __syncthreads();

    const int na = t >> 3, v8 = t & 7;   // PV/output mapping: n=na, v in [8*v8, 8*v8+8)
    float acc[4][8];
#pragma unroll
    for (int h = 0; h < 4; ++h)
#pragma unroll
        for (int i = 0; i < 8; ++i) acc[h][i] = 0.f;

    // content term: acc = Q[h,na,:] @ lam_c[:, v8*8..+8]
    for (int k = 0; k < 16; ++k) {
        float qh[4];
#pragma unroll
        for (int h = 0; h < 4; ++h)
            qh[h] = qkv[(size_t)(b * kOC + h * 16 + k) * kM + n0 + na];
        const float* L = &lam_s[k][v8 * 8];
#pragma unroll
        for (int i = 0; i < 8; ++i) {
            const float lv = L[i];
#pragma unroll
            for (int h = 0; h < 4; ++h) acc[h][i] += qh[h] * lv;
        }
    }

    // S-phase mapping: nl = t&31, this thread computes ml in [4*mo, 4*mo+4)
    const int nl = t & 31, mo = t >> 5;
    float Qr[4][16];
#pragma unroll
    for (int h = 0; h < 4; ++h)
#pragma unroll
        for (int k = 0; k < 16; ++k)
            Qr[h][k] = qkv[(size_t)(b * kOC + h * 16 + k) * kM + n0 + nl];

    for (int mrow = 0; mrow < 32; ++mrow) {
        const int dr = mrow - nrow + 31;      // in [0,62]
        const int mbase = mrow * 32;

        // stage rpe[dr][0..62][0..15]
        for (int e = t; e < 1008; e += 256)
            Rs[e >> 4][e & 15] = rpe[(size_t)(dr * 63) * 16 + e];
        // stage V[mbase..+32][0..63]
#pragma unroll
        for (int j = 0; j < 8; ++j) {
            int e = t + 256 * j;
            int v = e >> 5, ml = e & 31;
            Vs[ml][v] = qkv[(size_t)(b * kOC + 80 + v) * kM + mbase + ml];
        }
        __syncthreads();

        // S[h][nl][ml] = Qr[h] . Rs[ml-nl+31]
#pragma unroll
        for (int i = 0; i < 4; ++i) {
            const int ml = mo * 4 + i;
            const int dc = ml - nl + 31;
            const float* R = &Rs[dc][0];
            const float4 ra = *(const float4*)(R + 0);
            const float4 rb = *(const float4*)(R + 4);
            const float4 rc = *(const float4*)(R + 8);
            const float4 rd = *(const float4*)(R + 12);
            float s[4];
#pragma unroll
            for (int h = 0; h < 4; ++h) {
                const float* q = Qr[h];
                s[h] = q[0]*ra.x + q[1]*ra.y + q[2]*ra.z + q[3]*ra.w
                     + q[4]*rb.x + q[5]*rb.y + q[6]*rb.z + q[7]*rb.w
                     + q[8]*rc.x + q[9]*rc.y + q[10]*rc.z + q[11]*rc.w
                     + q[12]*rd.x + q[13]*rd.y + q[14]*rd.z + q[15]*rd.w;
            }
            S4[ml][nl] = make_float4(s[0], s[1], s[2], s[3]);
        }
        __syncthreads();

        // acc[h][v] += S[h][na][ml] * V[ml][v]
#pragma unroll 4
        for (int ml = 0; ml < 32; ++ml) {
            const float4 sv = S4[ml][na];
            const float* Vp = &Vs[ml][v8 * 8];
            const float4 va = *(const float4*)Vp;
            const float4 vb = *(const float4*)(Vp + 4);
            const float svh[4] = {sv.x, sv.y, sv.z, sv.w};
            const float vv8[8] = {va.x, va.y, va.z, va.w, vb.x, vb.y, vb.z, vb.w};
#pragma unroll
            for (int h = 0; h < 4; ++h)
#pragma unroll
                for (int i = 0; i < 8; ++i)
                    acc[h][i] += svh[h] * vv8[i];
        }
        __syncthreads();
    }

    float* ob = out + (size_t)(b * kM + n0 + na) * 256 + v8 * 8;
#pragma unroll
    for (int h = 0; h < 4; ++h) {
        float4 o1 = make_float4(acc[h][0], acc[h][1], acc[h][2], acc[h][3]);
        float4 o2 = make_float4(acc[h][4], acc[h][5], acc[h][6], acc[h][7]);
        *(float4*)(ob + h * 64)     = o1;
        *(float4*)(ob + h * 64 + 4) = o2;
    }
}

}  // namespace

extern "C" void kernel_launch(void* const* d_in, const int* in_sizes, int n_in,
                              void* d_out, int out_size, void* d_ws, size_t ws_size,
                              hipStream_t stream) {
    const float* x   = (const float*)d_in[0];
    const float* Wq  = (const float*)d_in[1];
    const float* Wk  = (const float*)d_in[2];
    const float* Wv  = (const float*)d_in[3];
    const float* gq  = (const float*)d_in[4];
    const float* bq  = (const float*)d_in[5];
    const float* mq  = (const float*)d_in[6];
    const float* vq  = (const float*)d_in[7];
    const float* gv  = (const float*)d_in[8];
    const float* bv  = (const float*)d_in[9];
    const float* mv  = (const float*)d_in[10];
    const float* vv  = (const float*)d_in[11];
    const float* rpe = (const float*)d_in[12];
    float* out = (float*)d_out;

    float* qkv       = (float*)d_ws;                        // 16*144*1024 floats
    float* lam_parts = qkv + (size_t)kB * kOC * kM;         // 8*16*16*64 floats

    k_qkv<<<dim3(16, 16), 256, 0, stream>>>(x, Wq, Wk, Wv, gq, bq, mq, vq,
                                            gv, bv, mv, vv, qkv);
    k_lam<<<dim3(8, 16), 256, 0, stream>>>(qkv, lam_parts);
    k_attn<<<dim3(32, 16), 256, 0, stream>>>(qkv, lam_parts, rpe, out);
}

// Round 2
// 221.882 us; speedup vs baseline: 1.5573x; 1.5573x over previous
//
#include <hip/hip_runtime.h>
#include <math.h>

namespace {
typedef unsigned short u16;
typedef __attribute__((ext_vector_type(4))) float f32x4;
typedef __attribute__((ext_vector_type(8))) short bf16x8;

constexpr int kB  = 16;
constexpr int kC  = 256;
constexpr int kM  = 1024;

__device__ inline u16 f2b(float f) {
    union { float f; unsigned u; } un; un.f = f;
    unsigned r = un.u + 0x7FFF + ((un.u >> 16) & 1);
    return (u16)(r >> 16);
}
__device__ inline float b2f(u16 u) {
    union { unsigned u; float f; } un; un.u = ((unsigned)u) << 16; return un.f;
}

// ---------------------------------------------------------------------------
// K1: fused conv1x1 (Q,K,V) + BN.
// Outputs: Qb bf16 [b][4h][1024n][32k] (k>=16 zero), Kf f32 [b][16][1024],
//          Vb bf16 [b][64v][1024m]
// grid (16 m-tiles, 16 b), block 256
// ---------------------------------------------------------------------------
__global__ __launch_bounds__(256) void k_qkv(
    const float* __restrict__ x,  const float* __restrict__ Wq,
    const float* __restrict__ Wk, const float* __restrict__ Wv,
    const float* __restrict__ gq, const float* __restrict__ bq,
    const float* __restrict__ mq, const float* __restrict__ vq,
    const float* __restrict__ gv, const float* __restrict__ bv,
    const float* __restrict__ mv, const float* __restrict__ vv,
    u16* __restrict__ Qb, float* __restrict__ Kf, u16* __restrict__ Vb)
{
    __shared__ float xs[64][68];
    __shared__ float Ws[64][145];

    const int b  = blockIdx.y;
    const int m0 = blockIdx.x * 64;
    const int t  = threadIdx.x;
    const int mi4 = (t & 15) * 4;
    const int ocg = t >> 4;

    float acc[9][4];
#pragma unroll
    for (int j = 0; j < 9; ++j)
#pragma unroll
        for (int i = 0; i < 4; ++i) acc[j][i] = 0.f;

    const int ciL = t & 63;
    const int ocq = t >> 6;

    for (int cc = 0; cc < 4; ++cc) {
        const int c0 = cc * 64;
#pragma unroll
        for (int j = 0; j < 16; ++j) {
            int e = t + 256 * j;
            int ci = e >> 6, mm = e & 63;
            xs[ci][mm] = x[(size_t)(b * kC + c0 + ci) * kM + m0 + mm];
        }
#pragma unroll
        for (int j = 0; j < 36; ++j) {
            int oc = ocq + 4 * j;
            const float* wrow = (oc < 64) ? (Wq + oc * kC)
                               : (oc < 80) ? (Wk + (oc - 64) * kC)
                                           : (Wv + (oc - 80) * kC);
            Ws[ciL][oc] = wrow[c0 + ciL];
        }
        __syncthreads();
#pragma unroll 8
        for (int ci = 0; ci < 64; ++ci) {
            const float4 xv = *(const float4*)&xs[ci][mi4];
#pragma unroll
            for (int j = 0; j < 9; ++j) {
                const float w = Ws[ci][ocg * 9 + j];
                acc[j][0] += w * xv.x;
                acc[j][1] += w * xv.y;
                acc[j][2] += w * xv.z;
                acc[j][3] += w * xv.w;
            }
        }
        __syncthreads();
    }

#pragma unroll
    for (int j = 0; j < 9; ++j) {
        const int oc = ocg * 9 + j;
        float s, bb;
        if (oc < 64)      { float inv = rsqrtf(vq[oc] + 1e-5f);      s = inv * gq[oc];      bb = bq[oc]      - mq[oc]      * s; }
        else if (oc < 80) { s = 1.f; bb = 0.f; }
        else              { int i2 = oc - 80; float inv = rsqrtf(vv[i2] + 1e-5f); s = inv * gv[i2]; bb = bv[i2] - mv[i2] * s; }
        float o[4];
#pragma unroll
        for (int i = 0; i < 4; ++i) o[i] = acc[j][i] * s + bb;

        if (oc < 64) {
            const int h = oc >> 4, k = oc & 15;
            u16* qp = Qb + ((size_t)(b * 4 + h) * kM + m0 + mi4) * 32 + k;
#pragma unroll
            for (int i = 0; i < 4; ++i) { qp[i * 32] = f2b(o[i]); qp[i * 32 + 16] = 0; }
        } else if (oc < 80) {
            float4 st; st.x = o[0]; st.y = o[1]; st.z = o[2]; st.w = o[3];
            *(float4*)&Kf[((size_t)b * 16 + oc - 64) * kM + m0 + mi4] = st;
        } else {
            u16 st[4] = {f2b(o[0]), f2b(o[1]), f2b(o[2]), f2b(o[3])};
            u16* vp = Vb + ((size_t)b * 64 + oc - 80) * kM + m0 + mi4;
            *(uint2*)vp = *(const uint2*)st;
        }
    }
}

// ---------------------------------------------------------------------------
// K2: sK = softmax_k(K); partial lam_c = sum_{m in block} sK[m,k] V[m,v]
// grid (8 m-blocks, 16 b), block 256. lam_parts[mb][b][k][v]
// ---------------------------------------------------------------------------
__global__ __launch_bounds__(256) void k_lam(
    const float* __restrict__ Kf, const u16* __restrict__ Vb,
    float* __restrict__ lam_parts)
{
    __shared__ float Ks[16][128];
    __shared__ float Vsh[64][129];

    const int b = blockIdx.y, mb = blockIdx.x;
    const int m0 = mb * 128;
    const int t = threadIdx.x;
    const float* Kc = Kf + (size_t)b * 16 * kM + m0;
    const u16*   Vc = Vb + (size_t)b * 64 * kM + m0;

#pragma unroll
    for (int j = 0; j < 8; ++j) {
        int e = t + 256 * j;
        Ks[e >> 7][e & 127] = Kc[(size_t)(e >> 7) * kM + (e & 127)];
    }
#pragma unroll
    for (int j = 0; j < 32; ++j) {
        int e = t + 256 * j;
        Vsh[e >> 7][e & 127] = b2f(Vc[(size_t)(e >> 7) * kM + (e & 127)]);
    }
    __syncthreads();

    if (t < 128) {
        float vals[16];
        float mx = -1e30f;
#pragma unroll
        for (int k = 0; k < 16; ++k) { vals[k] = Ks[k][t]; mx = fmaxf(mx, vals[k]); }
        float sum = 0.f;
#pragma unroll
        for (int k = 0; k < 16; ++k) { vals[k] = __expf(vals[k] - mx); sum += vals[k]; }
        const float inv = 1.f / sum;
#pragma unroll
        for (int k = 0; k < 16; ++k) Ks[k][t] = vals[k] * inv;
    }
    __syncthreads();

    const int v = t & 63, kq = t >> 6;
    float a[4] = {0.f, 0.f, 0.f, 0.f};
    for (int mm = 0; mm < 128; ++mm) {
        const float vv_ = Vsh[v][mm];
#pragma unroll
        for (int j = 0; j < 4; ++j) a[j] += Ks[kq * 4 + j][mm] * vv_;
    }
    float* o = lam_parts + (size_t)(mb * kB + b) * 1024;
#pragma unroll
    for (int j = 0; j < 4; ++j) o[(kq * 4 + j) * 64 + v] = a[j];
}

// ---------------------------------------------------------------------------
// K2b: lam_c = sum of 8 partials -> Vl bf16 [b][64v][32k] (k>=16 zero)
// grid 16, block 256
// ---------------------------------------------------------------------------
__global__ __launch_bounds__(256) void k_lam2(
    const float* __restrict__ lam_parts, u16* __restrict__ Vl)
{
    __shared__ float lc[1024];
    const int b = blockIdx.x, t = threadIdx.x;
    for (int e = t; e < 1024; e += 256) {
        float s = 0.f;
#pragma unroll
        for (int p = 0; p < 8; ++p) s += lam_parts[(size_t)(p * kB + b) * 1024 + e];
        lc[e] = s;                 // e = k*64 + v
    }
    __syncthreads();
    for (int e = t; e < 2048; e += 256) {
        int v = e >> 5, k = e & 31;
        Vl[((size_t)b * 64 + v) * 32 + k] = (k < 16) ? f2b(lc[k * 64 + v]) : (u16)0;
    }
}

// ---------------------------------------------------------------------------
// K2c: rpe f32 [63][63][16] -> rpe_b bf16 [63dr][64dc][32k] (pad dc=63, k>=16 zero)
// grid 63, block 256
// ---------------------------------------------------------------------------
__global__ __launch_bounds__(256) void k_rpe(
    const float* __restrict__ rpe, u16* __restrict__ rpe_b)
{
    const int dr = blockIdx.x, t = threadIdx.x;
    for (int e = t; e < 2048; e += 256) {
        int dc = e >> 5, k = e & 31;
        float v = (dc < 63 && k < 16) ? rpe[((size_t)dr * 63 + dc) * 16 + k] : 0.f;
        rpe_b[((size_t)dr * 64 + dc) * 32 + k] = f2b(v);
    }
}

// ---------------------------------------------------------------------------
// K3 (MFMA): out[b,n,h,v] = Q@lam_c + sum_m S[h,n,m] V[m,v]
// S via T^T = rpe_slab(64dc x 32k) @ Q^T(32k x 32nl), scatter-shifted to S[nl][ml].
// grid (32 nrow, 16 b), block 256 = 4 waves = 4 heads
// ---------------------------------------------------------------------------
__global__ __launch_bounds__(256) void k_attn(
    const u16* __restrict__ Qb, const u16* __restrict__ Vb,
    const u16* __restrict__ rpe_b, const u16* __restrict__ Vl,
    float* __restrict__ out)
{
    __shared__ u16 Rl[64][40];        // rpe slab: [dc][k]
    __shared__ u16 Vls[64][40];       // V slab:   [v][m_local]
    __shared__ u16 Sl[4][32][40];     // per-wave S: [nl][ml]

    const int b = blockIdx.y, nrow = blockIdx.x, n0 = nrow * 32;
    const int t = threadIdx.x;
    const int h = t >> 6, lane = t & 63, li = lane & 15, lg = lane >> 4;

    // Q fragments: lane holds Q[n0 + 16r + li][lg*8 + j]  (dual-use: T^T-B and content-A)
    const u16* Qbase = Qb + ((size_t)(b * 4 + h) * kM + n0) * 32;
    bf16x8 qf[2];
    qf[0] = *(const bf16x8*)&Qbase[(size_t)li * 32 + lg * 8];
    qf[1] = *(const bf16x8*)&Qbase[(size_t)(16 + li) * 32 + lg * 8];

    // content init: acc[r][c] = Q @ lam_c
    f32x4 acc[2][4];
    const u16* Vlb = Vl + (size_t)b * 64 * 32;
#pragma unroll
    for (int c = 0; c < 4; ++c) {
        bf16x8 cb = *(const bf16x8*)&Vlb[(size_t)(16 * c + li) * 32 + lg * 8];
        f32x4 z = {0.f, 0.f, 0.f, 0.f};
        acc[0][c] = __builtin_amdgcn_mfma_f32_16x16x32_bf16(qf[0], cb, z, 0, 0, 0);
        acc[1][c] = __builtin_amdgcn_mfma_f32_16x16x32_bf16(qf[1], cb, z, 0, 0, 0);
    }

    const int srow = t >> 2, schk = (t & 3) * 8;
    const u16* Vbb = Vb + (size_t)b * 64 * kM;
    u16* Sh = &Sl[h][0][0];

    for (int mrow = 0; mrow < 32; ++mrow) {
        const int dr = mrow - nrow + 31;
        const int mbase = mrow * 32;
        __syncthreads();
        *(bf16x8*)&Rl[srow][schk]  = *(const bf16x8*)&rpe_b[((size_t)dr * 64 + srow) * 32 + schk];
        *(bf16x8*)&Vls[srow][schk] = *(const bf16x8*)&Vbb[(size_t)srow * kM + mbase + schk];
        __syncthreads();

        // T^T phase: tiles (g: dc, r: nl)
        f32x4 tg[4][2];
#pragma unroll
        for (int g = 0; g < 4; ++g) {
            bf16x8 ra = *(const bf16x8*)&Rl[16 * g + li][lg * 8];
            f32x4 z = {0.f, 0.f, 0.f, 0.f};
            tg[g][0] = __builtin_amdgcn_mfma_f32_16x16x32_bf16(ra, qf[0], z, 0, 0, 0);
            tg[g][1] = __builtin_amdgcn_mfma_f32_16x16x32_bf16(ra, qf[1], z, 0, 0, 0);
        }

        // scatter T^T -> S[nl][ml], ml = dc + nl - 31
#pragma unroll
        for (int g = 0; g < 4; ++g)
#pragma unroll
            for (int r = 0; r < 2; ++r) {
                const int nl = 16 * r + li;
                const int dcb = 16 * g + 4 * lg;
#pragma unroll
                for (int reg = 0; reg < 4; ++reg) {
                    const int ml = dcb + reg + nl - 31;
                    if ((unsigned)ml < 32u) Sh[nl * 40 + ml] = f2b(tg[g][r][reg]);
                }
            }

        // PV: acc[r][c] += S(32n x 32m) @ V(32m x 64v)
        bf16x8 vf[4];
#pragma unroll
        for (int c = 0; c < 4; ++c)
            vf[c] = *(const bf16x8*)&Vls[16 * c + li][lg * 8];
#pragma unroll
        for (int r = 0; r < 2; ++r) {
            bf16x8 sa = *(const bf16x8*)&Sh[(size_t)(16 * r + li) * 40 + lg * 8];
#pragma unroll
            for (int c = 0; c < 4; ++c)
                acc[r][c] = __builtin_amdgcn_mfma_f32_16x16x32_bf16(sa, vf[c], acc[r][c], 0, 0, 0);
        }
    }

    // epilogue: D layout row = lg*4+reg, col = li
    float* ob = out + ((size_t)b * kM + n0) * 256 + h * 64;
#pragma unroll
    for (int r = 0; r < 2; ++r)
#pragma unroll
        for (int c = 0; c < 4; ++c)
#pragma unroll
            for (int reg = 0; reg < 4; ++reg)
                ob[(size_t)(16 * r + 4 * lg + reg) * 256 + 16 * c + li] = acc[r][c][reg];
}

}  // namespace

extern "C" void kernel_launch(void* const* d_in, const int* in_sizes, int n_in,
                              void* d_out, int out_size, void* d_ws, size_t ws_size,
                              hipStream_t stream) {
    const float* x   = (const float*)d_in[0];
    const float* Wq  = (const float*)d_in[1];
    const float* Wk  = (const float*)d_in[2];
    const float* Wv  = (const float*)d_in[3];
    const float* gq  = (const float*)d_in[4];
    const float* bq  = (const float*)d_in[5];
    const float* mq  = (const float*)d_in[6];
    const float* vq  = (const float*)d_in[7];
    const float* gv  = (const float*)d_in[8];
    const float* bv  = (const float*)d_in[9];
    const float* mv  = (const float*)d_in[10];
    const float* vv  = (const float*)d_in[11];
    const float* rpe = (const float*)d_in[12];
    float* out = (float*)d_out;

    float* Kf        = (float*)d_ws;                       // 16*16*1024 f32
    float* lam_parts = Kf + (size_t)16 * 16 * 1024;        // 8*16*1024 f32
    u16*   Qb        = (u16*)(lam_parts + (size_t)8 * 16 * 1024);  // 16*4*1024*32
    u16*   Vb        = Qb + (size_t)16 * 4 * 1024 * 32;    // 16*64*1024
    u16*   Vl        = Vb + (size_t)16 * 64 * 1024;        // 16*64*32
    u16*   rpe_b     = Vl + (size_t)16 * 64 * 32;          // 63*64*32

    k_qkv<<<dim3(16, 16), 256, 0, stream>>>(x, Wq, Wk, Wv, gq, bq, mq, vq,
                                            gv, bv, mv, vv, Qb, Kf, Vb);
    k_rpe<<<63, 256, 0, stream>>>(rpe, rpe_b);
    k_lam<<<dim3(8, 16), 256, 0, stream>>>(Kf, Vb, lam_parts);
    k_lam2<<<16, 256, 0, stream>>>(lam_parts, Vl);
    k_attn<<<dim3(32, 16), 256, 0, stream>>>(Qb, Vb, rpe_b, Vl, out);
}

// Round 3
// 167.114 us; speedup vs baseline: 2.0677x; 1.3277x over previous
//
#include <hip/hip_runtime.h>
#include <math.h>

namespace {
typedef unsigned short u16;
typedef __attribute__((ext_vector_type(4))) float f32x4;
typedef __attribute__((ext_vector_type(8))) short bf16x8;

constexpr int kB  = 16;
constexpr int kC  = 256;
constexpr int kM  = 1024;

__device__ inline u16 f2b(float f) {
    union { float f; unsigned u; } un; un.f = f;
    unsigned r = un.u + 0x7FFF + ((un.u >> 16) & 1);
    return (u16)(r >> 16);
}
__device__ inline float b2f(u16 u) {
    union { unsigned u; float f; } un; un.u = ((unsigned)u) << 16; return un.f;
}

// ---------------------------------------------------------------------------
// K0: pack W (BN-scale folded) -> Wb bf16 [144][256], bias bb f32 [144]
// oc 0..63 Q, 64..79 K (no BN), 80..143 V.  grid 9, block 256
// ---------------------------------------------------------------------------
__global__ __launch_bounds__(256) void k_wpack(
    const float* __restrict__ Wq, const float* __restrict__ Wk,
    const float* __restrict__ Wv,
    const float* __restrict__ gq, const float* __restrict__ bq,
    const float* __restrict__ mq, const float* __restrict__ vq,
    const float* __restrict__ gv, const float* __restrict__ bv,
    const float* __restrict__ mv, const float* __restrict__ vv,
    u16* __restrict__ Wb, float* __restrict__ bb)
{
    const int t = threadIdx.x;
    const int oc = blockIdx.x * 16 + (t >> 4);
    const int c0 = (t & 15) * 16;
    float s, bias;
    const float* wrow;
    if (oc < 64)      { float inv = rsqrtf(vq[oc] + 1e-5f); s = inv * gq[oc]; bias = bq[oc] - mq[oc] * s; wrow = Wq + (size_t)oc * kC; }
    else if (oc < 80) { s = 1.f; bias = 0.f; wrow = Wk + (size_t)(oc - 64) * kC; }
    else              { int i2 = oc - 80; float inv = rsqrtf(vv[i2] + 1e-5f); s = inv * gv[i2]; bias = bv[i2] - mv[i2] * s; wrow = Wv + (size_t)i2 * kC; }
#pragma unroll
    for (int cc = 0; cc < 16; ++cc)
        Wb[(size_t)oc * kC + c0 + cc] = f2b(wrow[c0 + cc] * s);
    if (c0 == 0) bb[oc] = bias;
}

// ---------------------------------------------------------------------------
// K1 (MFMA): conv1x1 via C[144oc][64m] = Wb @ X-tile.
// Outputs: Qb bf16 [b][4h][1024n][32k] (k>=16 zero), Kf f32 [b][16][1024],
//          Vb bf16 [b][64v][1024m].  grid (16 mtile, 16 b), block 256 (4 waves)
// ---------------------------------------------------------------------------
__global__ __launch_bounds__(256) void k_qkv(
    const float* __restrict__ x, const u16* __restrict__ Wb,
    const float* __restrict__ bb,
    u16* __restrict__ Qb, float* __restrict__ Kf, u16* __restrict__ Vb)
{
    __shared__ float Xs[256][64];   // 64 KB, [c][m]

    const int b  = blockIdx.y;
    const int m0 = blockIdx.x * 64;
    const int t  = threadIdx.x;
    const int wv = t >> 6, lane = t & 63, li = lane & 15, lg = lane >> 4;
    const int mw = wv * 16;         // wave's m-offset within tile

    // stage X tile [256c][64m] f32, coalesced float4
#pragma unroll
    for (int j = 0; j < 16; ++j) {
        int e = t + 256 * j;                 // over [c][m4]
        int c = e >> 4, m4 = (e & 15) * 4;
        float4 xv = *(const float4*)&x[(size_t)(b * kC + c) * kM + m0 + m4];
        *(float4*)&Xs[c][m4] = xv;
    }
    __syncthreads();

    f32x4 acc[9];
#pragma unroll
    for (int i = 0; i < 9; ++i) acc[i] = (f32x4){0.f, 0.f, 0.f, 0.f};

#pragma unroll 2
    for (int ch = 0; ch < 8; ++ch) {
        const int c0 = ch * 32 + lg * 8;
        // B-frag: X[c0..c0+8][m = m0+mw+li]
        float xf[8];
#pragma unroll
        for (int j = 0; j < 8; ++j) xf[j] = Xs[c0 + j][mw + li];
        bf16x8 bfr;
#pragma unroll
        for (int j = 0; j < 8; ++j) bfr[j] = (short)f2b(xf[j]);
        // A-frags from global Wb (L1/L2-resident), 9 tiles
#pragma unroll
        for (int tl = 0; tl < 9; ++tl) {
            bf16x8 afr = *(const bf16x8*)&Wb[(size_t)(tl * 16 + li) * kC + c0];
            acc[tl] = __builtin_amdgcn_mfma_f32_16x16x32_bf16(afr, bfr, acc[tl], 0, 0, 0);
        }
    }

    // epilogue: D row = oc_in_tile = lg*4+reg, col = m_in_tile = li
    const int m = m0 + mw + li;
#pragma unroll
    for (int tl = 0; tl < 9; ++tl) {
        const int ocb = tl * 16 + lg * 4;
        float o[4];
#pragma unroll
        for (int reg = 0; reg < 4; ++reg) o[reg] = acc[tl][reg] + bb[ocb + reg];

        if (tl < 4) {                         // Q: h=tl, k=lg*4+reg
            u16 pk[4];
#pragma unroll
            for (int reg = 0; reg < 4; ++reg) pk[reg] = f2b(o[reg]);
            u16* qp = Qb + ((size_t)(b * 4 + tl) * kM + m) * 32;
            *(uint2*)&qp[lg * 4]      = *(const uint2*)pk;
            uint2 z; z.x = 0u; z.y = 0u;
            *(uint2*)&qp[16 + lg * 4] = z;
        } else if (tl == 4) {                 // K: f32
#pragma unroll
            for (int reg = 0; reg < 4; ++reg)
                Kf[(size_t)(b * 16 + lg * 4 + reg) * kM + m] = o[reg];
        } else {                              // V
            const int vb = (tl - 5) * 16 + lg * 4;
#pragma unroll
            for (int reg = 0; reg < 4; ++reg)
                Vb[(size_t)(b * 64 + vb + reg) * kM + m] = f2b(o[reg]);
        }
    }
}

// ---------------------------------------------------------------------------
// K2: sK = softmax_k(K); partial lam_c = sum_{m in block} sK[m,k] V[m,v]
// grid (16 m-blocks, 16 b), block 256. lam_parts[mb][b][k][v]
// ---------------------------------------------------------------------------
__global__ __launch_bounds__(256) void k_lam(
    const float* __restrict__ Kf, const u16* __restrict__ Vb,
    float* __restrict__ lam_parts)
{
    __shared__ float Ks[16][64];
    __shared__ float Vsh[64][69];

    const int b = blockIdx.y, mb = blockIdx.x;
    const int m0 = mb * 64;
    const int t = threadIdx.x;
    const float* Kc = Kf + (size_t)b * 16 * kM + m0;
    const u16*   Vc = Vb + (size_t)b * 64 * kM + m0;

#pragma unroll
    for (int j = 0; j < 4; ++j) {
        int e = t + 256 * j;
        Ks[e >> 6][e & 63] = Kc[(size_t)(e >> 6) * kM + (e & 63)];
    }
#pragma unroll
    for (int j = 0; j < 16; ++j) {
        int e = t + 256 * j;
        Vsh[e >> 6][e & 63] = b2f(Vc[(size_t)(e >> 6) * kM + (e & 63)]);
    }
    __syncthreads();

    if (t < 64) {
        float vals[16];
        float mx = -1e30f;
#pragma unroll
        for (int k = 0; k < 16; ++k) { vals[k] = Ks[k][t]; mx = fmaxf(mx, vals[k]); }
        float sum = 0.f;
#pragma unroll
        for (int k = 0; k < 16; ++k) { vals[k] = __expf(vals[k] - mx); sum += vals[k]; }
        const float inv = 1.f / sum;
#pragma unroll
        for (int k = 0; k < 16; ++k) Ks[k][t] = vals[k] * inv;
    }
    __syncthreads();

    const int v = t & 63, kq = t >> 6;
    float a[4] = {0.f, 0.f, 0.f, 0.f};
#pragma unroll 4
    for (int mm = 0; mm < 64; ++mm) {
        const float vv_ = Vsh[v][mm];
#pragma unroll
        for (int j = 0; j < 4; ++j) a[j] += Ks[kq * 4 + j][mm] * vv_;
    }
    float* o = lam_parts + (size_t)(mb * kB + b) * 1024;
#pragma unroll
    for (int j = 0; j < 4; ++j) o[(kq * 4 + j) * 64 + v] = a[j];
}

// ---------------------------------------------------------------------------
// K2b: lam_c = sum of 16 partials -> Vl bf16 [b][64v][32k] (k>=16 zero)
// grid 16, block 256
// ---------------------------------------------------------------------------
__global__ __launch_bounds__(256) void k_lam2(
    const float* __restrict__ lam_parts, u16* __restrict__ Vl)
{
    __shared__ float lc[1024];
    const int b = blockIdx.x, t = threadIdx.x;
    for (int e = t; e < 1024; e += 256) {
        float s = 0.f;
#pragma unroll
        for (int p = 0; p < 16; ++p) s += lam_parts[(size_t)(p * kB + b) * 1024 + e];
        lc[e] = s;                 // e = k*64 + v
    }
    __syncthreads();
    for (int e = t; e < 2048; e += 256) {
        int v = e >> 5, k = e & 31;
        Vl[((size_t)b * 64 + v) * 32 + k] = (k < 16) ? f2b(lc[k * 64 + v]) : (u16)0;
    }
}

// ---------------------------------------------------------------------------
// K2c: rpe f32 [63][63][16] -> rpe_b bf16 [63dr][64dc][32k]
// grid 63, block 256
// ---------------------------------------------------------------------------
__global__ __launch_bounds__(256) void k_rpe(
    const float* __restrict__ rpe, u16* __restrict__ rpe_b)
{
    const int dr = blockIdx.x, t = threadIdx.x;
    for (int e = t; e < 2048; e += 256) {
        int dc = e >> 5, k = e & 31;
        float v = (dc < 63 && k < 16) ? rpe[((size_t)dr * 63 + dc) * 16 + k] : 0.f;
        rpe_b[((size_t)dr * 64 + dc) * 32 + k] = f2b(v);
    }
}

// ---------------------------------------------------------------------------
// K3 (MFMA): out[b,n,h,v] = Q@lam_c + sum_m S[h,n,m] V[m,v]
// grid (32 nrow, 16 b), block 256 = 4 waves = 4 heads
// ---------------------------------------------------------------------------
__global__ __launch_bounds__(256) void k_attn(
    const u16* __restrict__ Qb, const u16* __restrict__ Vb,
    const u16* __restrict__ rpe_b, const u16* __restrict__ Vl,
    float* __restrict__ out)
{
    __shared__ u16 Rl[64][40];        // rpe slab: [dc][k]
    __shared__ u16 Vls[64][40];       // V slab:   [v][m_local]
    __shared__ u16 Sl[4][32][40];     // per-wave S: [nl][ml]

    const int b = blockIdx.y, nrow = blockIdx.x, n0 = nrow * 32;
    const int t = threadIdx.x;
    const int h = t >> 6, lane = t & 63, li = lane & 15, lg = lane >> 4;

    const u16* Qbase = Qb + ((size_t)(b * 4 + h) * kM + n0) * 32;
    bf16x8 qf[2];
    qf[0] = *(const bf16x8*)&Qbase[(size_t)li * 32 + lg * 8];
    qf[1] = *(const bf16x8*)&Qbase[(size_t)(16 + li) * 32 + lg * 8];

    f32x4 acc[2][4];
    const u16* Vlb = Vl + (size_t)b * 64 * 32;
#pragma unroll
    for (int c = 0; c < 4; ++c) {
        bf16x8 cb = *(const bf16x8*)&Vlb[(size_t)(16 * c + li) * 32 + lg * 8];
        f32x4 z = {0.f, 0.f, 0.f, 0.f};
        acc[0][c] = __builtin_amdgcn_mfma_f32_16x16x32_bf16(qf[0], cb, z, 0, 0, 0);
        acc[1][c] = __builtin_amdgcn_mfma_f32_16x16x32_bf16(qf[1], cb, z, 0, 0, 0);
    }

    const int srow = t >> 2, schk = (t & 3) * 8;
    const u16* Vbb = Vb + (size_t)b * 64 * kM;
    u16* Sh = &Sl[h][0][0];

    for (int mrow = 0; mrow < 32; ++mrow) {
        const int dr = mrow - nrow + 31;
        const int mbase = mrow * 32;
        __syncthreads();
        *(bf16x8*)&Rl[srow][schk]  = *(const bf16x8*)&rpe_b[((size_t)dr * 64 + srow) * 32 + schk];
        *(bf16x8*)&Vls[srow][schk] = *(const bf16x8*)&Vbb[(size_t)srow * kM + mbase + schk];
        __syncthreads();

        f32x4 tg[4][2];
#pragma unroll
        for (int g = 0; g < 4; ++g) {
            bf16x8 ra = *(const bf16x8*)&Rl[16 * g + li][lg * 8];
            f32x4 z = {0.f, 0.f, 0.f, 0.f};
            tg[g][0] = __builtin_amdgcn_mfma_f32_16x16x32_bf16(ra, qf[0], z, 0, 0, 0);
            tg[g][1] = __builtin_amdgcn_mfma_f32_16x16x32_bf16(ra, qf[1], z, 0, 0, 0);
        }

#pragma unroll
        for (int g = 0; g < 4; ++g)
#pragma unroll
            for (int r = 0; r < 2; ++r) {
                const int nl = 16 * r + li;
                const int dcb = 16 * g + 4 * lg;
#pragma unroll
                for (int reg = 0; reg < 4; ++reg) {
                    const int ml = dcb + reg + nl - 31;
                    if ((unsigned)ml < 32u) Sh[nl * 40 + ml] = f2b(tg[g][r][reg]);
                }
            }

        bf16x8 vf[4];
#pragma unroll
        for (int c = 0; c < 4; ++c)
            vf[c] = *(const bf16x8*)&Vls[16 * c + li][lg * 8];
#pragma unroll
        for (int r = 0; r < 2; ++r) {
            bf16x8 sa = *(const bf16x8*)&Sh[(size_t)(16 * r + li) * 40 + lg * 8];
#pragma unroll
            for (int c = 0; c < 4; ++c)
                acc[r][c] = __builtin_amdgcn_mfma_f32_16x16x32_bf16(sa, vf[c], acc[r][c], 0, 0, 0);
        }
    }

    float* ob = out + ((size_t)b * kM + n0) * 256 + h * 64;
#pragma unroll
    for (int r = 0; r < 2; ++r)
#pragma unroll
        for (int c = 0; c < 4; ++c)
#pragma unroll
            for (int reg = 0; reg < 4; ++reg)
                ob[(size_t)(16 * r + 4 * lg + reg) * 256 + 16 * c + li] = acc[r][c][reg];
}

}  // namespace

extern "C" void kernel_launch(void* const* d_in, const int* in_sizes, int n_in,
                              void* d_out, int out_size, void* d_ws, size_t ws_size,
                              hipStream_t stream) {
    const float* x   = (const float*)d_in[0];
    const float* Wq  = (const float*)d_in[1];
    const float* Wk  = (const float*)d_in[2];
    const float* Wv  = (const float*)d_in[3];
    const float* gq  = (const float*)d_in[4];
    const float* bq  = (const float*)d_in[5];
    const float* mq  = (const float*)d_in[6];
    const float* vq  = (const float*)d_in[7];
    const float* gv  = (const float*)d_in[8];
    const float* bv  = (const float*)d_in[9];
    const float* mv  = (const float*)d_in[10];
    const float* vv  = (const float*)d_in[11];
    const float* rpe = (const float*)d_in[12];
    float* out = (float*)d_out;

    float* Kf        = (float*)d_ws;                                 // 16*16*1024 f32
    float* lam_parts = Kf + (size_t)16 * 16 * 1024;                  // 16*16*1024 f32
    float* bbuf      = lam_parts + (size_t)16 * 16 * 1024;           // 144 f32
    u16*   Qb        = (u16*)(bbuf + 256);                           // 16*4*1024*32
    u16*   Vb        = Qb + (size_t)16 * 4 * 1024 * 32;              // 16*64*1024
    u16*   Vl        = Vb + (size_t)16 * 64 * 1024;                  // 16*64*32
    u16*   rpe_b     = Vl + (size_t)16 * 64 * 32;                    // 63*64*32
    u16*   Wb        = rpe_b + (size_t)63 * 64 * 32;                 // 144*256

    k_wpack<<<9, 256, 0, stream>>>(Wq, Wk, Wv, gq, bq, mq, vq, gv, bv, mv, vv,
                                   Wb, bbuf);
    k_qkv<<<dim3(16, 16), 256, 0, stream>>>(x, Wb, bbuf, Qb, Kf, Vb);
    k_rpe<<<63, 256, 0, stream>>>(rpe, rpe_b);
    k_lam<<<dim3(16, 16), 256, 0, stream>>>(Kf, Vb, lam_parts);
    k_lam2<<<16, 256, 0, stream>>>(lam_parts, Vl);
    k_attn<<<dim3(32, 16), 256, 0, stream>>>(Qb, Vb, rpe_b, Vl, out);
}

// Round 4
// 158.281 us; speedup vs baseline: 2.1831x; 1.0558x over previous
//
#include <hip/hip_runtime.h>
#include <math.h>

namespace {
typedef unsigned short u16;
typedef __attribute__((ext_vector_type(4))) float f32x4;
typedef __attribute__((ext_vector_type(8))) short bf16x8;

constexpr int kB  = 16;
constexpr int kC  = 256;
constexpr int kM  = 1024;

__device__ inline u16 f2b(float f) {
    union { float f; unsigned u; } un; un.f = f;
    unsigned r = un.u + 0x7FFF + ((un.u >> 16) & 1);
    return (u16)(r >> 16);
}
__device__ inline float b2f(u16 u) {
    union { unsigned u; float f; } un; un.u = ((unsigned)u) << 16; return un.f;
}

// ---------------------------------------------------------------------------
// K0: blocks 0..8: pack W (BN folded) -> Wb bf16 [144][256], bias bb f32
//     blocks 9..71: rpe f32 [63][63][16] -> rpe_b bf16 [63dr][64dc][32k]
// ---------------------------------------------------------------------------
__global__ __launch_bounds__(256) void k_prep(
    const float* __restrict__ Wq, const float* __restrict__ Wk,
    const float* __restrict__ Wv,
    const float* __restrict__ gq, const float* __restrict__ bq,
    const float* __restrict__ mq, const float* __restrict__ vq,
    const float* __restrict__ gv, const float* __restrict__ bv,
    const float* __restrict__ mv, const float* __restrict__ vv,
    const float* __restrict__ rpe,
    u16* __restrict__ Wb, float* __restrict__ bb, u16* __restrict__ rpe_b)
{
    const int bid = blockIdx.x;
    const int t = threadIdx.x;
    if (bid < 9) {
        const int oc = bid * 16 + (t >> 4);
        const int c0 = (t & 15) * 16;
        float s, bias;
        const float* wrow;
        if (oc < 64)      { float inv = rsqrtf(vq[oc] + 1e-5f); s = inv * gq[oc]; bias = bq[oc] - mq[oc] * s; wrow = Wq + (size_t)oc * kC; }
        else if (oc < 80) { s = 1.f; bias = 0.f; wrow = Wk + (size_t)(oc - 64) * kC; }
        else              { int i2 = oc - 80; float inv = rsqrtf(vv[i2] + 1e-5f); s = inv * gv[i2]; bias = bv[i2] - mv[i2] * s; wrow = Wv + (size_t)i2 * kC; }
#pragma unroll
        for (int cc = 0; cc < 16; ++cc)
            Wb[(size_t)oc * kC + c0 + cc] = f2b(wrow[c0 + cc] * s);
        if (c0 == 0) bb[oc] = bias;
    } else {
        const int dr = bid - 9;
        for (int e = t; e < 2048; e += 256) {
            int dc = e >> 5, k = e & 31;
            float v = (dc < 63 && k < 16) ? rpe[((size_t)dr * 63 + dc) * 16 + k] : 0.f;
            rpe_b[((size_t)dr * 64 + dc) * 32 + k] = f2b(v);
        }
    }
}

// ---------------------------------------------------------------------------
// K1 (MFMA): conv1x1.  grid (32 mtile of 32, 16 b), block 256 (4 waves)
// waves: mh = w&1 (m-half), tg = w>>1 (tiles 0..4 | 5..8)
// ---------------------------------------------------------------------------
__global__ __launch_bounds__(256) void k_qkv(
    const float* __restrict__ x, const u16* __restrict__ Wb,
    const float* __restrict__ bb,
    u16* __restrict__ Qb, float* __restrict__ Kf, u16* __restrict__ Vb)
{
    __shared__ float Xs[256][36];   // 36 KB

    const int b  = blockIdx.y;
    const int m0 = blockIdx.x * 32;
    const int t  = threadIdx.x;
    const int w  = t >> 6, lane = t & 63, li = lane & 15, lg = lane >> 4;
    const int mh = w & 1, tg = w >> 1;
    const int mw = mh * 16;

    // stage X tile [256c][32m] f32
#pragma unroll
    for (int j = 0; j < 8; ++j) {
        int e = t + 256 * j;                 // 2048 float4
        int c = e >> 3, m4 = (e & 7) * 4;
        *(float4*)&Xs[c][m4] = *(const float4*)&x[(size_t)(b * kC + c) * kM + m0 + m4];
    }
    __syncthreads();

    const int m = m0 + mw + li;

    if (tg == 0) {
        f32x4 acc[5];
#pragma unroll
        for (int i = 0; i < 5; ++i) acc[i] = (f32x4){0.f, 0.f, 0.f, 0.f};
#pragma unroll 2
        for (int ch = 0; ch < 8; ++ch) {
            const int c0 = ch * 32 + lg * 8;
            bf16x8 bfr;
#pragma unroll
            for (int j = 0; j < 8; ++j) bfr[j] = (short)f2b(Xs[c0 + j][mw + li]);
#pragma unroll
            for (int i = 0; i < 5; ++i) {
                bf16x8 afr = *(const bf16x8*)&Wb[(size_t)(i * 16 + li) * kC + c0];
                acc[i] = __builtin_amdgcn_mfma_f32_16x16x32_bf16(afr, bfr, acc[i], 0, 0, 0);
            }
        }
#pragma unroll
        for (int i = 0; i < 5; ++i) {
            const int ocb = i * 16 + lg * 4;
            float o[4];
#pragma unroll
            for (int reg = 0; reg < 4; ++reg) o[reg] = acc[i][reg] + bb[ocb + reg];
            if (i < 4) {                      // Q tile, h=i, k=lg*4+reg
                u16 pk[4];
#pragma unroll
                for (int reg = 0; reg < 4; ++reg) pk[reg] = f2b(o[reg]);
                u16* qp = Qb + ((size_t)(b * 4 + i) * kM + m) * 32;
                *(uint2*)&qp[lg * 4] = *(const uint2*)pk;
                uint2 z; z.x = 0u; z.y = 0u;
                *(uint2*)&qp[16 + lg * 4] = z;
            } else {                          // K f32
#pragma unroll
                for (int reg = 0; reg < 4; ++reg)
                    Kf[(size_t)(b * 16 + lg * 4 + reg) * kM + m] = o[reg];
            }
        }
    } else {
        f32x4 acc[4];
#pragma unroll
        for (int i = 0; i < 4; ++i) acc[i] = (f32x4){0.f, 0.f, 0.f, 0.f};
#pragma unroll 2
        for (int ch = 0; ch < 8; ++ch) {
            const int c0 = ch * 32 + lg * 8;
            bf16x8 bfr;
#pragma unroll
            for (int j = 0; j < 8; ++j) bfr[j] = (short)f2b(Xs[c0 + j][mw + li]);
#pragma unroll
            for (int i = 0; i < 4; ++i) {
                bf16x8 afr = *(const bf16x8*)&Wb[(size_t)((5 + i) * 16 + li) * kC + c0];
                acc[i] = __builtin_amdgcn_mfma_f32_16x16x32_bf16(afr, bfr, acc[i], 0, 0, 0);
            }
        }
#pragma unroll
        for (int i = 0; i < 4; ++i) {
            const int ocb = (5 + i) * 16 + lg * 4;
            const int vb = i * 16 + lg * 4;
#pragma unroll
            for (int reg = 0; reg < 4; ++reg) {
                float o = acc[i][reg] + bb[ocb + reg];
                Vb[(size_t)(b * 64 + vb + reg) * kM + m] = f2b(o);
            }
        }
    }
}

// ---------------------------------------------------------------------------
// K2: sK = softmax_k(K); partial lam_c = sum_{m in blk} sK[m,k] V[m,v]
// grid (16 mb, 16 b), block 256.  lam_parts[mb][b][k][v]
// ---------------------------------------------------------------------------
__global__ __launch_bounds__(256) void k_lam(
    const float* __restrict__ Kf, const u16* __restrict__ Vb,
    float* __restrict__ lam_parts)
{
    __shared__ float Ks[16][64];
    __shared__ float Vsh[64][69];

    const int b = blockIdx.y, mb = blockIdx.x;
    const int m0 = mb * 64;
    const int t = threadIdx.x;
    const float* Kc = Kf + (size_t)b * 16 * kM + m0;
    const u16*   Vc = Vb + (size_t)b * 64 * kM + m0;

#pragma unroll
    for (int j = 0; j < 4; ++j) {
        int e = t + 256 * j;
        Ks[e >> 6][e & 63] = Kc[(size_t)(e >> 6) * kM + (e & 63)];
    }
#pragma unroll
    for (int j = 0; j < 4; ++j) {
        int e = t + 256 * j;
        int v = e >> 4, mq = (e & 15) * 4;
        uint2 pv = *(const uint2*)&Vc[(size_t)v * kM + mq];
        u16 pp[4]; *(uint2*)pp = pv;
#pragma unroll
        for (int i = 0; i < 4; ++i) Vsh[v][mq + i] = b2f(pp[i]);
    }
    __syncthreads();

    if (t < 64) {
        float vals[16];
        float mx = -1e30f;
#pragma unroll
        for (int k = 0; k < 16; ++k) { vals[k] = Ks[k][t]; mx = fmaxf(mx, vals[k]); }
        float sum = 0.f;
#pragma unroll
        for (int k = 0; k < 16; ++k) { vals[k] = __expf(vals[k] - mx); sum += vals[k]; }
        const float inv = 1.f / sum;
#pragma unroll
        for (int k = 0; k < 16; ++k) Ks[k][t] = vals[k] * inv;
    }
    __syncthreads();

    const int v = t & 63, kq = t >> 6;
    float a[4] = {0.f, 0.f, 0.f, 0.f};
#pragma unroll 4
    for (int mm = 0; mm < 64; ++mm) {
        const float vv_ = Vsh[v][mm];
#pragma unroll
        for (int j = 0; j < 4; ++j) a[j] += Ks[kq * 4 + j][mm] * vv_;
    }
    float* o = lam_parts + (size_t)(mb * kB + b) * 1024;
#pragma unroll
    for (int j = 0; j < 4; ++j) o[(kq * 4 + j) * 64 + v] = a[j];
}

// ---------------------------------------------------------------------------
// K3 (MFMA): out = Q@lam_c + position.  grid (32 nrow, 16 b), block 256.
// 16 iters x 64-m chunk; register prefetch of next R/V slabs.
// ---------------------------------------------------------------------------
__global__ __launch_bounds__(256) void k_attn(
    const u16* __restrict__ Qb, const u16* __restrict__ Vb,
    const u16* __restrict__ rpe_b, const float* __restrict__ lam_parts,
    float* __restrict__ out)
{
    __shared__ u16 Rl[128][40];       // [mi*64 + dc][k]   10,240 B
    __shared__ u16 Vls[64][72];       // [v][ml 0..63]      9,216 B
    __shared__ u16 Sl[4][32][72];     // per-wave S        18,432 B
    __shared__ float lc[16][65];      // lam_c              4,160 B

    const int b = blockIdx.y, nrow = blockIdx.x, n0 = nrow * 32;
    const int t = threadIdx.x;
    const int h = t >> 6, lane = t & 63, li = lane & 15, lg = lane >> 4;
    const u16* Vbb = Vb + (size_t)b * 64 * kM;
    u16* Sh = &Sl[h][0][0];

    // lam_c = sum of 16 partials
    for (int e = t; e < 1024; e += 256) {
        float s = 0.f;
#pragma unroll
        for (int p = 0; p < 16; ++p) s += lam_parts[(size_t)(p * kB + b) * 1024 + e];
        lc[e >> 6][e & 63] = s;
    }

    // Q fragments
    const u16* Qbase = Qb + ((size_t)(b * 4 + h) * kM + n0) * 32;
    bf16x8 qf[2];
    qf[0] = *(const bf16x8*)&Qbase[(size_t)li * 32 + lg * 8];
    qf[1] = *(const bf16x8*)&Qbase[(size_t)(16 + li) * 32 + lg * 8];

    // prefetch iter 0 slabs into regs
    bf16x8 rpre[2], vpre[2];
#pragma unroll
    for (int ii = 0; ii < 2; ++ii) {
        int s = 2 * t + ii;
        int rrow = s >> 2, rkc = (s & 3) * 8;
        int dr = (rrow >> 6) - nrow + 31;
        rpre[ii] = *(const bf16x8*)&rpe_b[((size_t)dr * 64 + (rrow & 63)) * 32 + rkc];
        int v = s >> 3, mc = (s & 7) * 8;
        vpre[ii] = *(const bf16x8*)&Vbb[(size_t)v * kM + mc];
    }

    __syncthreads();   // lc ready

    // content term
    f32x4 acc[2][4];
#pragma unroll
    for (int c = 0; c < 4; ++c) {
        bf16x8 cb;
#pragma unroll
        for (int j = 0; j < 8; ++j) {
            int k = lg * 8 + j;
            cb[j] = (k < 16) ? (short)f2b(lc[k][16 * c + li]) : (short)0;
        }
        f32x4 z = {0.f, 0.f, 0.f, 0.f};
        acc[0][c] = __builtin_amdgcn_mfma_f32_16x16x32_bf16(qf[0], cb, z, 0, 0, 0);
        acc[1][c] = __builtin_amdgcn_mfma_f32_16x16x32_bf16(qf[1], cb, z, 0, 0, 0);
    }

    for (int it = 0; it < 16; ++it) {
        __syncthreads();             // previous iter done reading LDS
        // write prefetched regs
#pragma unroll
        for (int ii = 0; ii < 2; ++ii) {
            int s = 2 * t + ii;
            *(bf16x8*)&Rl[s >> 2][(s & 3) * 8] = rpre[ii];
            *(bf16x8*)&Vls[s >> 3][(s & 7) * 8] = vpre[ii];
        }
        __syncthreads();
        // issue next iter's loads (land during compute)
        if (it < 15) {
            const int itn = it + 1;
#pragma unroll
            for (int ii = 0; ii < 2; ++ii) {
                int s = 2 * t + ii;
                int rrow = s >> 2, rkc = (s & 3) * 8;
                int dr = 2 * itn + (rrow >> 6) - nrow + 31;
                rpre[ii] = *(const bf16x8*)&rpe_b[((size_t)dr * 64 + (rrow & 63)) * 32 + rkc];
                int v = s >> 3, mc = (s & 7) * 8;
                vpre[ii] = *(const bf16x8*)&Vbb[(size_t)v * kM + itn * 64 + mc];
            }
        }

        // compute 2 m-rows
#pragma unroll
        for (int mi = 0; mi < 2; ++mi) {
            f32x4 tq[4][2];
#pragma unroll
            for (int g = 0; g < 4; ++g) {
                bf16x8 ra = *(const bf16x8*)&Rl[mi * 64 + 16 * g + li][lg * 8];
                f32x4 z = {0.f, 0.f, 0.f, 0.f};
                tq[g][0] = __builtin_amdgcn_mfma_f32_16x16x32_bf16(ra, qf[0], z, 0, 0, 0);
                tq[g][1] = __builtin_amdgcn_mfma_f32_16x16x32_bf16(ra, qf[1], z, 0, 0, 0);
            }
#pragma unroll
            for (int g = 0; g < 4; ++g)
#pragma unroll
                for (int r = 0; r < 2; ++r) {
                    const int nl = 16 * r + li;
                    const int dcb = 16 * g + 4 * lg;
#pragma unroll
                    for (int reg = 0; reg < 4; ++reg) {
                        const int ml = dcb + reg + nl - 31;
                        if ((unsigned)ml < 32u)
                            Sh[nl * 72 + mi * 32 + ml] = f2b(tq[g][r][reg]);
                    }
                }

            bf16x8 vfc[4];
#pragma unroll
            for (int c = 0; c < 4; ++c)
                vfc[c] = *(const bf16x8*)&Vls[16 * c + li][mi * 32 + lg * 8];
#pragma unroll
            for (int r = 0; r < 2; ++r) {
                bf16x8 sa = *(const bf16x8*)&Sh[(size_t)(16 * r + li) * 72 + mi * 32 + lg * 8];
#pragma unroll
                for (int c = 0; c < 4; ++c)
                    acc[r][c] = __builtin_amdgcn_mfma_f32_16x16x32_bf16(sa, vfc[c], acc[r][c], 0, 0, 0);
            }
        }
    }

    float* ob = out + ((size_t)b * kM + n0) * 256 + h * 64;
#pragma unroll
    for (int r = 0; r < 2; ++r)
#pragma unroll
        for (int c = 0; c < 4; ++c)
#pragma unroll
            for (int reg = 0; reg < 4; ++reg)
                ob[(size_t)(16 * r + 4 * lg + reg) * 256 + 16 * c + li] = acc[r][c][reg];
}

}  // namespace

extern "C" void kernel_launch(void* const* d_in, const int* in_sizes, int n_in,
                              void* d_out, int out_size, void* d_ws, size_t ws_size,
                              hipStream_t stream) {
    const float* x   = (const float*)d_in[0];
    const float* Wq  = (const float*)d_in[1];
    const float* Wk  = (const float*)d_in[2];
    const float* Wv  = (const float*)d_in[3];
    const float* gq  = (const float*)d_in[4];
    const float* bq  = (const float*)d_in[5];
    const float* mq  = (const float*)d_in[6];
    const float* vq  = (const float*)d_in[7];
    const float* gv  = (const float*)d_in[8];
    const float* bv  = (const float*)d_in[9];
    const float* mv  = (const float*)d_in[10];
    const float* vv  = (const float*)d_in[11];
    const float* rpe = (const float*)d_in[12];
    float* out = (float*)d_out;

    float* Kf        = (float*)d_ws;                                 // 16*16*1024 f32
    float* lam_parts = Kf + (size_t)16 * 16 * 1024;                  // 16*16*1024 f32
    float* bbuf      = lam_parts + (size_t)16 * 16 * 1024;           // 144 f32
    u16*   Qb        = (u16*)(bbuf + 256);                           // 16*4*1024*32
    u16*   Vb        = Qb + (size_t)16 * 4 * 1024 * 32;              // 16*64*1024
    u16*   rpe_b     = Vb + (size_t)16 * 64 * 1024;                  // 63*64*32
    u16*   Wb        = rpe_b + (size_t)63 * 64 * 32;                 // 144*256

    k_prep<<<72, 256, 0, stream>>>(Wq, Wk, Wv, gq, bq, mq, vq, gv, bv, mv, vv,
                                   rpe, Wb, bbuf, rpe_b);
    k_qkv<<<dim3(32, 16), 256, 0, stream>>>(x, Wb, bbuf, Qb, Kf, Vb);
    k_lam<<<dim3(16, 16), 256, 0, stream>>>(Kf, Vb, lam_parts);
    k_attn<<<dim3(32, 16), 256, 0, stream>>>(Qb, Vb, rpe_b, lam_parts, out);
}